// Round 1
// 427.430 us; speedup vs baseline: 1.0532x; 1.0532x over previous
//
#include <hip/hip_runtime.h>
#include <cmath>

#define NB 16
#define NL 64
#define NP 512
#define NH 128
#define NG 10
#define ROWS (NB * NL * NP)          // 524288 rows

// output layout (flat float32, reference return order)
#define OFF_PI    ((size_t)0)
#define OFF_SIGMA ((size_t)5242880)
#define OFF_MU    ((size_t)10485760)
#define OFF_DIST  ((size_t)15728640)
#define OFF_MASK  ((size_t)16252928)

// ---------------------------------------------------------------------------
// Fused kernel: min-dist over 24 atoms + 3x GEMV [128 -> 10] + activations.
// One thread per (b, l, p) == one row of Interact. 256 rows per block.
//
// X (Interact) is staged through LDS with coalesced 128B-segment loads
// (the per-thread-row float4 pattern was a 512B-stride scatter -> L1 thrash).
// Weights are read with wave-uniform indices -> compiler emits s_load ->
// SGPR operand in v_fma (scalar pipe, zero VALU/LDS cost).
// ---------------------------------------------------------------------------
__global__ __launch_bounds__(256, 4) void k_fused(
    const float* __restrict__ pos_l,   // [B, NL, 3]
    const float* __restrict__ pos_p,   // [B, NP, 24, 3]
    const int*   __restrict__ mask,    // [B, NL, NP] (bool as int32)
    const float* __restrict__ X,       // [ROWS, 128]
    const float* __restrict__ Wpi, const float* __restrict__ bpi,
    const float* __restrict__ Wsg, const float* __restrict__ bsg,
    const float* __restrict__ Wmu, const float* __restrict__ bmu,
    float* __restrict__ out_pi,
    float* __restrict__ out_sg,
    float* __restrict__ out_mu,
    float* __restrict__ dist_out,
    float* __restrict__ mask_out)
{
    // [256 rows][32 k] staging tile, padded 32->33 floats: read addr
    // tid*33 + k -> bank (tid+k)%32, 2 lanes/bank across the wave = free.
    __shared__ float xs[256 * 33];

    const int tid = threadIdx.x;
    const int idx = blockIdx.x * 256 + tid;     // b*NL*NP + l*NP + p

    // ---------------- distance part ----------------
    {
        int p  = idx & (NP - 1);
        int bl = idx >> 9;                      // b*NL + l
        int b  = bl >> 6;

        const float* xl = pos_l + bl * 3;
        float x0 = xl[0], x1 = xl[1], x2 = xl[2];
        float qs = x0 * x0 + x1 * x1 + x2 * x2;

        // 24 atoms * 3 floats = 18 float4 per residue (288B rows, 16B aligned)
        const float4* yp = (const float4*)(pos_p + ((size_t)(b * NP + p)) * 72);

        // min over clamped d2; d2<0 would be NaN->10000 in the reference,
        // so map it to 1e8 (=10000^2, exact) and take a single sqrt at the end.
        float m2 = 1e30f;
        #pragma unroll
        for (int q = 0; q < 6; ++q) {           // 4 atoms per iteration
            float4 v0 = yp[q * 3 + 0];
            float4 v1 = yp[q * 3 + 1];
            float4 v2 = yp[q * 3 + 2];
            float c[12] = {v0.x, v0.y, v0.z, v0.w,
                           v1.x, v1.y, v1.z, v1.w,
                           v2.x, v2.y, v2.z, v2.w};
            #pragma unroll
            for (int a = 0; a < 4; ++a) {
                float yx = c[a * 3 + 0], yy = c[a * 3 + 1], yz = c[a * 3 + 2];
                float d2 = qs + (yx * yx + yy * yy + yz * yz)
                              - 2.0f * (x0 * yx + x1 * yy + x2 * yz);
                d2 = (d2 >= 0.0f) ? d2 : 1e8f;  // sqrt(1e8) == 10000.0f exactly
                m2 = fminf(m2, d2);
            }
        }
        float m = sqrtf(m2);

        int mk = mask[idx];
        dist_out[idx] = mk ? m : 0.0f;
        mask_out[idx] = mk ? 1.0f : 0.0f;
    }

    // ---------------- GEMV part ----------------
    float accp[NG], accs[NG], accm[NG];
    #pragma unroll
    for (int g = 0; g < NG; ++g) {              // uniform-index -> s_load
        accp[g] = bpi[g];
        accs[g] = bsg[g];
        accm[g] = bmu[g];
    }

    const size_t row0 = (size_t)blockIdx.x * 256;

    for (int kc = 0; kc < 4; ++kc) {            // 4 stages of 32 k each
        __syncthreads();                        // reads of prev stage done
        // Cooperative load: 256 rows x 32 k. slot s = j*256+tid,
        // row = s>>3, k4 = s&7 -> each wave covers 8 rows x 128B contiguous.
        #pragma unroll
        for (int j = 0; j < 8; ++j) {
            int s  = j * 256 + tid;
            int r  = s >> 3;
            int k4 = s & 7;
            float4 v = *(const float4*)(X + (row0 + r) * NH + kc * 32 + k4 * 4);
            float* d = &xs[r * 33 + k4 * 4];    // stride 33 -> scalar writes
            d[0] = v.x; d[1] = v.y; d[2] = v.z; d[3] = v.w;
        }
        __syncthreads();

        const float* xr = &xs[tid * 33];
        #pragma unroll 4
        for (int k = 0; k < 32; ++k) {
            float h = xr[k];
            int kk = kc * 32 + k;               // wave-uniform
            const float* wp = Wpi + kk * NG;
            const float* ws = Wsg + kk * NG;
            const float* wm = Wmu + kk * NG;
            #pragma unroll
            for (int g = 0; g < NG; ++g) {
                accp[g] = fmaf(h, wp[g], accp[g]);
                accs[g] = fmaf(h, ws[g], accs[g]);
                accm[g] = fmaf(h, wm[g], accm[g]);
            }
        }
    }

    // ---------------- epilogue ----------------
    size_t ro = (size_t)idx * NG;

    // pi = softmax(accp)
    float mx = accp[0];
    #pragma unroll
    for (int g = 1; g < NG; ++g) mx = fmaxf(mx, accp[g]);
    float e[NG], ssum = 0.0f;
    #pragma unroll
    for (int g = 0; g < NG; ++g) { e[g] = __expf(accp[g] - mx); ssum += e[g]; }
    float inv = 1.0f / ssum;
    #pragma unroll
    for (int g = 0; g < NG; ++g) out_pi[ro + g] = e[g] * inv;

    // sigma = clip(leaky(accs) + 1.1, 1e-6, inf)
    #pragma unroll
    for (int g = 0; g < NG; ++g) {
        float x = accs[g];
        float v = (x >= 0.0f ? x : 0.01f * x) + 1.1f;
        out_sg[ro + g] = fmaxf(v, 1e-6f);
    }

    // mu = leaky(accm) + 1.0
    #pragma unroll
    for (int g = 0; g < NG; ++g) {
        float x = accm[g];
        out_mu[ro + g] = (x >= 0.0f ? x : 0.01f * x) + 1.0f;
    }
}

// ---------------------------------------------------------------------------
extern "C" void kernel_launch(void* const* d_in, const int* in_sizes, int n_in,
                              void* d_out, int out_size, void* d_ws, size_t ws_size,
                              hipStream_t stream) {
    const float* pos_l    = (const float*)d_in[0];
    const float* pos_p    = (const float*)d_in[1];
    const float* Interact = (const float*)d_in[2];
    const int*   mask     = (const int*)  d_in[3];
    const float* Wpi      = (const float*)d_in[4];
    const float* bpi      = (const float*)d_in[5];
    const float* Wsg      = (const float*)d_in[6];
    const float* bsg      = (const float*)d_in[7];
    const float* Wmu      = (const float*)d_in[8];
    const float* bmu      = (const float*)d_in[9];

    float* out      = (float*)d_out;
    float* out_pi   = out + OFF_PI;
    float* out_sg   = out + OFF_SIGMA;
    float* out_mu   = out + OFF_MU;
    float* out_dist = out + OFF_DIST;
    float* out_mask = out + OFF_MASK;

    hipLaunchKernelGGL(k_fused, dim3(ROWS / 256), dim3(256), 0, stream,
                       pos_l, pos_p, mask, Interact,
                       Wpi, bpi, Wsg, bsg, Wmu, bmu,
                       out_pi, out_sg, out_mu, out_dist, out_mask);
}